// Round 11
// baseline (1667.772 us; speedup 1.0000x reference)
//
#include <hip/hip_runtime.h>
#include <math.h>

// ---------- problem constants ----------
constexpr int SEQ_T = 72;
constexpr int FDIM  = 64;
constexpr int UNITS = 256;
constexpr int U4    = 1024;
constexpr int BATCH = 4096;
constexpr int BM    = 32;          // batch rows per block
constexpr int NKC   = 10;          // k-chunks of 32 (x: kc0-1, h: kc2-9)

// LDS (dynamic):
//   A blob (single parity): [10 kc][2 m][64 lanes][8 shorts] = 10240 shorts = 20480 B
//   ring: 16 waves x 2 slots x 4096 B = 131072 B
constexpr int A_SH      = NKC * 2 * 64 * 8;            // 10240 shorts
constexpr int OFF_RING  = A_SH * 2;                    // 20480 B
constexpr int RING_W    = 2 * 4096;                    // per-wave ring bytes
constexpr int LDS_BYTES = OFF_RING + 16 * RING_W;      // 151552 B

using bf16x8 = __attribute__((ext_vector_type(8))) short;
using f32x4  = __attribute__((ext_vector_type(4))) float;

__device__ __forceinline__ float sigmoid_fast(float x) {
    return 1.0f / (1.0f + __expf(-x));
}
__device__ __forceinline__ float tanh_fast(float x) {
    float ax = fabsf(x);
    float e  = __expf(2.0f * ax);
    float t  = 1.0f - 2.0f / (e + 1.0f);
    return copysignf(t, x);
}
__device__ __forceinline__ unsigned short f2bf(float f) {
    union { float f; unsigned u; } v; v.f = f;
    unsigned r = (v.u + 0x7FFFu + ((v.u >> 16) & 1u)) >> 16;   // RNE
    return (unsigned short)r;
}

// ---------- prep: z-weights as per-wave MFMA B-fragment blobs ----------
// blob idx = ((w*10 + kc)*4 + ct)*64 + l  (w = wave 0..15 owning units [w*16,w*16+16))
// col = ct*256 + w*16 + (l&15)  (ct = gate) ; k = kc*32 + (l>>4)*8 + e
__global__ void prep_wblob(const float* __restrict__ W, const float* __restrict__ U,
                           unsigned short* __restrict__ Wblob) {
    int id = blockIdx.x * 256 + threadIdx.x;    // 40960
    int l    = id & 63;
    int ct   = (id >> 6) & 3;
    int rest = id >> 8;                          // w*10 + kc
    int kc   = rest % 10, w = rest / 10;
    int col  = ct * 256 + w * 16 + (l & 15);
    int kb   = kc * 32 + (l >> 4) * 8;
    bf16x8 v;
    #pragma unroll
    for (int e = 0; e < 8; ++e) {
        int k = kb + e;
        float f = (k < FDIM) ? W[(size_t)k * U4 + col] : U[(size_t)(k - FDIM) * U4 + col];
        v[e] = (short)f2bf(f);
    }
    *reinterpret_cast<bf16x8*>(Wblob + (size_t)id * 8) = v;
}

// ---------- prep: dense weights as B-fragment blobs ----------
// blob idx = (ft*8 + kcd)*64 + l ; f = ft*16 + (l&15); k = kcd*32 + (l>>4)*8 + e
__global__ void prep_wdblob(const float* __restrict__ Wd, unsigned short* __restrict__ Wdblob) {
    int id = blockIdx.x * 256 + threadIdx.x;    // 2048
    int l   = id & 63;
    int kcd = (id >> 6) & 7;
    int ft  = id >> 9;
    int f   = ft * 16 + (l & 15);
    int kb  = kcd * 32 + (l >> 4) * 8;
    bf16x8 v;
    #pragma unroll
    for (int e = 0; e < 8; ++e)
        v[e] = (short)f2bf(Wd[(size_t)(kb + e) * FDIM + f]);
    *reinterpret_cast<bf16x8*>(Wdblob + (size_t)id * 8) = v;
}

__device__ __forceinline__ void gload16_lds(const unsigned short* g, char* l) {
    __builtin_amdgcn_global_load_lds(
        (const __attribute__((address_space(1))) void*)g,
        (__attribute__((address_space(3))) void*)l, 16, 0, 0);
}

// ---------- persistent, fully block-local LSTM ----------
// grid 128 x 1024 (16 waves, 1 block/CU). Block owns 32 batch rows, ALL 1024 z-cols;
// wave w owns units [w*16,w*16+16) x 4 gates (ct=gate).
// Weights streamed per step via global_load_lds into a PER-WAVE 2-slot LDS ring with
// hand-counted vmcnt(4) waits (T3/T4): loads stay in flight across consume points,
// no barriers in the stream (wave-private slots), exact counts (__syncthreads drains
// vmcnt). [x|h] in a single-parity fragment-ordered LDS blob (extra barrier B2).
__global__ __launch_bounds__(1024, 4) void lstm_persistent(
    const float* __restrict__ inputs,          // [B][72][64] fp32
    const float* __restrict__ bias,            // [1024] fp32
    const unsigned short* __restrict__ Wblob,  // frag-ordered z-weights (640 KB)
    const unsigned short* __restrict__ Wdblob, // frag-ordered dense weights (32 KB)
    const float* __restrict__ bd,              // [64] fp32
    float* __restrict__ out,                   // [B][out_steps][64] fp32
    int out_steps)
{
    extern __shared__ char smem[];
    unsigned short* A_s = (unsigned short*)smem;            // [10][2][64][8] shorts

    const int tid  = threadIdx.x;
    const int w    = tid >> 6, lane = tid & 63;
    const int l16  = lane & 15, hi4 = lane >> 4;
    const int bb   = blockIdx.x * BM;
    char* ringw = smem + OFF_RING + w * RING_W;             // wave-private ring

    // ---- zero h region of A (kc2-9, both m): shorts [2048, 10240) ----
    *reinterpret_cast<bf16x8*>(A_s + 2048 + tid * 8) = (bf16x8){0,0,0,0,0,0,0,0};

    float bz[4];
    #pragma unroll
    for (int g = 0; g < 4; ++g) bz[g] = bias[g * 256 + w * 16 + l16];
    const float bdv = (w < 8) ? bd[(w >> 1) * 16 + l16] : 0.0f;

    float c_reg[2][4];
    #pragma unroll
    for (int mt = 0; mt < 2; ++mt)
        #pragma unroll
        for (int j = 0; j < 4; ++j) c_reg[mt][j] = 0.0f;

    // wave's weight-blob base (per-lane); kc stride 2048 shorts, ct stride 512
    const unsigned short* wbase = Wblob + ((size_t)(w * 10) * 4 * 64 + lane) * 8;
    const int tmax = SEQ_T + out_steps - 1;    // 95

    #pragma unroll 1
    for (int t = 0; ; ++t) {
        if (t < SEQ_T) {
            // ---- stage x(t) -> A kc0,1 (coalesced float2/thread) ----
            int r = tid >> 5, c2 = (tid & 31) * 2;
            float2 v = *reinterpret_cast<const float2*>(
                inputs + ((size_t)(bb + r) * SEQ_T + t) * FDIM + c2);
            unsigned lo = f2bf(v.x), hi = f2bf(v.y);
            int kcx = c2 >> 5, m = r >> 4;
            int ls  = (r & 15) | (((c2 >> 3) & 3) << 4);
            *reinterpret_cast<unsigned int*>(
                &A_s[((kcx * 2 + m) * 64 + ls) * 8 + (c2 & 7)]) = lo | (hi << 16);
        } else {
            __syncthreads();                   // B0: h_t (epilogue writes) visible
            // ---- dense head: pred = h @ Wd + bd (waves 0-7: ft=w>>1, mt=w&1) ----
            if (w < 8) {
                const int ft = w >> 1, mt = w & 1;
                f32x4 accp = {0.f, 0.f, 0.f, 0.f};
                #pragma unroll
                for (int kcd = 0; kcd < 8; ++kcd) {
                    bf16x8 a = *reinterpret_cast<const bf16x8*>(
                        &A_s[(((2 + kcd) * 2 + mt) * 64 + lane) * 8]);
                    bf16x8 bfr = *reinterpret_cast<const bf16x8*>(
                        Wdblob + (size_t)(((ft * 8 + kcd) * 64) + lane) * 8);
                    accp = __builtin_amdgcn_mfma_f32_16x16x32_bf16(a, bfr, accp, 0, 0, 0);
                }
                const int s = t - SEQ_T;
                const int f = ft * 16 + l16;
                const int kcx = f >> 5;
                const int lsh = ((f >> 3) & 3) << 4;
                #pragma unroll
                for (int j = 0; j < 4; ++j) {
                    int rr = mt * 16 + hi4 * 4 + j;
                    float v = accp[j] + bdv;
                    out[((size_t)(bb + rr) * out_steps + s) * FDIM + f] = v;
                    A_s[((kcx * 2 + mt) * 64 + ((rr & 15) | lsh)) * 8 + (f & 7)] = f2bf(v);
                }
            }
            if (t == tmax) break;
        }
        __syncthreads();                       // B1: A staged; vmcnt drained to 0

        // ================ z = [x|h] @ [W;U] : ring-streamed weights ================
        // prologue: kc0 -> slot0, kc1 -> slot1 (8 DMA loads in flight)
        #pragma unroll
        for (int ct = 0; ct < 4; ++ct)
            gload16_lds(wbase + 0 * 2048 + ct * 512, ringw + 0 * 4096 + ct * 1024);
        #pragma unroll
        for (int ct = 0; ct < 4; ++ct)
            gload16_lds(wbase + 1 * 2048 + ct * 512, ringw + 1 * 4096 + ct * 1024);

        f32x4 acc[2][4];
        #pragma unroll
        for (int mt = 0; mt < 2; ++mt)
            #pragma unroll
            for (int g = 0; g < 4; ++g) acc[mt][g] = (f32x4){0.f, 0.f, 0.f, 0.f};

        #pragma unroll
        for (int kc = 0; kc < NKC; ++kc) {
            if (kc < 9) asm volatile("s_waitcnt vmcnt(4)" ::: "memory");  // slot kc landed
            else        asm volatile("s_waitcnt vmcnt(0)" ::: "memory");
            __builtin_amdgcn_sched_barrier(0);

            bf16x8 a0 = *reinterpret_cast<const bf16x8*>(&A_s[((kc * 2 + 0) * 64 + lane) * 8]);
            bf16x8 a1 = *reinterpret_cast<const bf16x8*>(&A_s[((kc * 2 + 1) * 64 + lane) * 8]);
            bf16x8 br[4];
            #pragma unroll
            for (int ct = 0; ct < 4; ++ct)
                br[ct] = *reinterpret_cast<const bf16x8*>(
                    ringw + (kc & 1) * 4096 + ct * 1024 + lane * 16);

            #pragma unroll
            for (int ct = 0; ct < 4; ++ct) {
                acc[0][ct] = __builtin_amdgcn_mfma_f32_16x16x32_bf16(a0, br[ct], acc[0][ct], 0, 0, 0);
                acc[1][ct] = __builtin_amdgcn_mfma_f32_16x16x32_bf16(a1, br[ct], acc[1][ct], 0, 0, 0);
            }

            if (kc + 2 < NKC) {
                // ring reads of this slot must be complete before DMA re-fills it
                asm volatile("s_waitcnt lgkmcnt(0)" ::: "memory");
                __builtin_amdgcn_sched_barrier(0);
                #pragma unroll
                for (int ct = 0; ct < 4; ++ct)
                    gload16_lds(wbase + (size_t)(kc + 2) * 2048 + ct * 512,
                                ringw + (kc & 1) * 4096 + ct * 1024);
            }
        }
        __syncthreads();                       // B2: all A reads done

        // ================ gates + state; h_{t+1} -> A kc 2..9 ================
        const int kch = 2 + (w >> 1);
        const int lsh = ((w * 2 + (l16 >> 3)) & 3) << 4;
        #pragma unroll
        for (int mt = 0; mt < 2; ++mt) {
            #pragma unroll
            for (int j = 0; j < 4; ++j) {
                float zi = acc[mt][0][j] + bz[0];
                float zf = acc[mt][1][j] + bz[1];
                float zg = acc[mt][2][j] + bz[2];
                float zo = acc[mt][3][j] + bz[3];
                float ig = sigmoid_fast(zi);
                float fg = sigmoid_fast(zf);
                float og = sigmoid_fast(zo);
                float cn = fg * c_reg[mt][j] + ig * tanh_fast(zg);
                c_reg[mt][j] = cn;
                float hv = og * tanh_fast(cn);
                int rl = hi4 * 4 + j;          // row & 15
                A_s[((kch * 2 + mt) * 64 + (rl | lsh)) * 8 + (l16 & 7)] = f2bf(hv);
            }
        }
    }
}

extern "C" void kernel_launch(void* const* d_in, const int* in_sizes, int n_in,
                              void* d_out, int out_size, void* d_ws, size_t ws_size,
                              hipStream_t stream) {
    const float* inputs = (const float*)d_in[0];
    const float* W      = (const float*)d_in[1];
    const float* U      = (const float*)d_in[2];
    const float* b      = (const float*)d_in[3];
    const float* Wd     = (const float*)d_in[4];
    const float* bd     = (const float*)d_in[5];
    float* out = (float*)d_out;

    const int out_steps = out_size / (BATCH * FDIM);   // 24

    char* ws = (char*)d_ws;
    unsigned short* Wblob  = (unsigned short*)(ws);               // 640 KB
    unsigned short* Wdblob = (unsigned short*)(ws + (1u << 20));  // 32 KB

    prep_wblob<<<160, 256, 0, stream>>>(W, U, Wblob);
    prep_wdblob<<<8, 256, 0, stream>>>(Wd, Wdblob);

    (void)hipFuncSetAttribute((const void*)lstm_persistent,
                              hipFuncAttributeMaxDynamicSharedMemorySize, LDS_BYTES);

    lstm_persistent<<<dim3(BATCH / BM), dim3(1024), LDS_BYTES, stream>>>(
        inputs, b, Wblob, Wdblob, bd, out, out_steps);
}

// Round 12
// 1048.552 us; speedup vs baseline: 1.5905x; 1.5905x over previous
//
#include <hip/hip_runtime.h>
#include <math.h>

// ---------- problem constants ----------
constexpr int SEQ_T = 72;
constexpr int FDIM  = 64;
constexpr int UNITS = 256;
constexpr int U4    = 1024;
constexpr int BATCH = 4096;
constexpr int NKC   = 10;          // k-chunks of 32 (x: kc0-1, h: kc2-9)

// Partition: 256 blocks = 64 row-groups (64 rows) x 4 unit-groups (64 units x 4 gates).
// Weights per block: 256 cols x 320 k x 2B = 160 KB -> 96 KB LDS (kc0-5) + 64 VGPR/lane (kc6-9).
// h exchanged via L3 (system-scope relaxed atomics); 1 global barrier/step.

// LDS (dynamic, shorts unless noted):
constexpr int A_SH    = NKC * 4 * 64 * 8;        // 20480 sh = 40960 B   [kc][m4][64][8]
constexpr int WL_SH   = 6 * 4 * 4 * 64 * 8;      // 49152 sh = 98304 B   [kc<6][ug][g][64][8]
constexpr int HST_SH  = 2 * 4 * 64 * 8;          // 4096 sh  = 8192 B    [kcb][m4][64][8]
constexpr int LDS_BYTES = (A_SH + WL_SH + HST_SH) * 2;   // 147456

using bf16x8 = __attribute__((ext_vector_type(8))) short;
using f32x4  = __attribute__((ext_vector_type(4))) float;

__device__ __forceinline__ float sigmoid_fast(float x) {
    return 1.0f / (1.0f + __expf(-x));
}
__device__ __forceinline__ float tanh_fast(float x) {
    float ax = fabsf(x);
    float e  = __expf(2.0f * ax);
    float t  = 1.0f - 2.0f / (e + 1.0f);
    return copysignf(t, x);
}
__device__ __forceinline__ unsigned short f2bf(float f) {
    union { float f; unsigned u; } v; v.f = f;
    unsigned r = (v.u + 0x7FFFu + ((v.u >> 16) & 1u)) >> 16;   // RNE
    return (unsigned short)r;
}
__device__ __forceinline__ bf16x8 pack8(float4 a, float4 b) {
    bf16x8 p;
    p[0] = (short)f2bf(a.x); p[1] = (short)f2bf(a.y);
    p[2] = (short)f2bf(a.z); p[3] = (short)f2bf(a.w);
    p[4] = (short)f2bf(b.x); p[5] = (short)f2bf(b.y);
    p[6] = (short)f2bf(b.z); p[7] = (short)f2bf(b.w);
    return p;
}

// ---------- prep: z-weights, blob idx = (((ub*10+kc)*4+ug)*4+g)*64 + l ----------
// col = g*256 + ub*64 + ug*16 + (l&15) ; k = kc*32 + (l>>4)*8 + e
__global__ void prep_wblob(const float* __restrict__ W, const float* __restrict__ U,
                           unsigned short* __restrict__ Wblob) {
    int id = blockIdx.x * 256 + threadIdx.x;    // 40960
    int l    = id & 63;
    int g    = (id >> 6) & 3;
    int ug   = (id >> 8) & 3;
    int rest = id >> 10;                         // ub*10 + kc
    int kc   = rest % 10, ub = rest / 10;
    int col  = g * 256 + ub * 64 + ug * 16 + (l & 15);
    int kb   = kc * 32 + (l >> 4) * 8;
    bf16x8 v;
    #pragma unroll
    for (int e = 0; e < 8; ++e) {
        int k = kb + e;
        float f = (k < FDIM) ? W[(size_t)k * U4 + col] : U[(size_t)(k - FDIM) * U4 + col];
        v[e] = (short)f2bf(f);
    }
    *reinterpret_cast<bf16x8*>(Wblob + (size_t)id * 8) = v;
}

// ---------- prep: dense weights, blob idx = (ft*8 + kcd)*64 + l ----------
__global__ void prep_wdblob(const float* __restrict__ Wd, unsigned short* __restrict__ Wdblob) {
    int id = blockIdx.x * 256 + threadIdx.x;    // 2048
    int l   = id & 63;
    int kcd = (id >> 6) & 7;
    int ft  = id >> 9;
    int f   = ft * 16 + (l & 15);
    int kb  = kcd * 32 + (l >> 4) * 8;
    bf16x8 v;
    #pragma unroll
    for (int e = 0; e < 8; ++e)
        v[e] = (short)f2bf(Wd[(size_t)(kb + e) * FDIM + f]);
    *reinterpret_cast<bf16x8*>(Wdblob + (size_t)id * 8) = v;
}

// system-scope relaxed 8B load/store (sc0/sc1 path: L3-coherent, no cache flushes)
__device__ __forceinline__ unsigned long long sysload(const unsigned long long* p) {
    return __hip_atomic_load(p, __ATOMIC_RELAXED, __HIP_MEMORY_SCOPE_SYSTEM);
}
__device__ __forceinline__ void sysstore(unsigned long long* p, unsigned long long v) {
    __hip_atomic_store(p, v, __ATOMIC_RELAXED, __HIP_MEMORY_SCOPE_SYSTEM);
}

// ---------- persistent unit-split LSTM: weights CU-resident ----------
// grid 256 x 512 (8 waves). blk = rg*4 + ub. Block owns rows [rg*64, +64),
// cols = units [ub*64,+64) x 4 gates. Wave w: ug = w&3 (16 units), rows half = w>>2.
// h goes through hbuf in L3 (system-scope); 1 global barrier per step.
__global__ __launch_bounds__(512, 1) void lstm_persistent(
    const float* __restrict__ inputs,          // [B][72][64] fp32
    const float* __restrict__ bias,            // [1024] fp32
    const unsigned short* __restrict__ Wblob,  // z-weight blobs (640 KB)
    const unsigned short* __restrict__ Wdblob, // dense blobs (32 KB)
    const float* __restrict__ bd,              // [64] fp32
    unsigned short* __restrict__ hbuf,         // [2][64 rg][8 kc][4 m][64][8] bf16
    unsigned int* __restrict__ barcnt,         // [1], zeroed per launch
    float* __restrict__ out,                   // [B][out_steps][64] fp32
    int out_steps)
{
    extern __shared__ char smem[];
    unsigned short* A_s = (unsigned short*)smem;                       // [10][4][64][8]
    unsigned short* WL  = (unsigned short*)(smem + A_SH * 2);          // [6][4][4][64][8]
    unsigned short* hst = (unsigned short*)(smem + (A_SH + WL_SH) * 2);// [2][4][64][8]

    const int tid  = threadIdx.x;
    const int w    = tid >> 6, lane = tid & 63;
    const int l16  = lane & 15, hi4 = lane >> 4;
    const int blk  = blockIdx.x;
    const int rg   = blk >> 2, ub = blk & 3;
    const int bb   = rg * 64;
    const int ug   = w & 3;                    // wave's 16-unit group within block
    const int m4a  = 2 * (w >> 2);             // wave's two row-16 tiles

    // ---- LDS weights kc0-5: contiguous 96 KB from Wblob[ub] (once) ----
    {
        const unsigned short* src = Wblob + (size_t)(ub * 10) * 16 * 512;
        #pragma unroll
        for (int i = 0; i < 12; ++i) {
            int idx = (i * 512 + tid) * 8;     // 49152 shorts as 16B chunks
            *reinterpret_cast<bf16x8*>(WL + idx) =
                *reinterpret_cast<const bf16x8*>(src + idx);
        }
    }
    // ---- register weights kc6-9 (wave's ug slice): 64 VGPRs ----
    bf16x8 Breg[4][4];
    #pragma unroll
    for (int i = 0; i < 4; ++i)
        #pragma unroll
        for (int g = 0; g < 4; ++g)
            Breg[i][g] = *reinterpret_cast<const bf16x8*>(
                Wblob + ((size_t)(((ub * 10 + 6 + i) * 4 + ug) * 4 + g) * 64 + lane) * 8);

    const int uu = ub * 64 + ug * 16 + l16;    // this lane's global unit
    float bz[4];
    #pragma unroll
    for (int g = 0; g < 4; ++g) bz[g] = bias[g * 256 + uu];
    const float bdv = bd[(w & 3) * 16 + l16];  // dense: ft = w&3

    float c_reg[2][4];
    #pragma unroll
    for (int m = 0; m < 2; ++m)
        #pragma unroll
        for (int j = 0; j < 4; ++j) c_reg[m][j] = 0.0f;

    const int tmax = SEQ_T + out_steps - 1;    // 95
    const size_t HB = (size_t)64 * 16384;      // parity stride (shorts)

    #pragma unroll 1
    for (int t = 0; ; ++t) {
        const int p = t & 1;

        // ---- stage h_t: hbuf[p][rg] (32 KB) -> A kc2-9, 8x8B per thread ----
        {
            const unsigned long long* src = reinterpret_cast<const unsigned long long*>(
                hbuf + p * HB + (size_t)rg * 16384);
            unsigned long long vbuf[8];
            #pragma unroll
            for (int i = 0; i < 8; ++i) vbuf[i] = sysload(src + (size_t)i * 512 + tid);
            #pragma unroll
            for (int i = 0; i < 8; ++i)
                *reinterpret_cast<unsigned long long*>(A_s + 4096 + (i * 512 + tid) * 4) = vbuf[i];
        }
        if (t < SEQ_T) {
            // ---- stage x(t): 8 floats/thread -> A kc0,1 ----
            int r = tid >> 3, c8 = (tid & 7) * 8;
            const float* xr = inputs + ((size_t)(bb + r) * SEQ_T + t) * FDIM + c8;
            bf16x8 pk = pack8(*reinterpret_cast<const float4*>(xr),
                              *reinterpret_cast<const float4*>(xr + 4));
            int kcx = c8 >> 5;
            int lb  = (r & 15) | ((((c8 & 31) >> 3) & 3) << 4);
            *reinterpret_cast<bf16x8*>(A_s + ((kcx * 4 + (r >> 4)) * 64 + lb) * 8) = pk;
            __syncthreads();                   // A ready
        } else {
            __syncthreads();                   // h staged
            // ---- dense head (redundant in all 4 blocks): tiles (ft=w&3, m4a/m4a+1) ----
            const int s = t - SEQ_T;
            const int f = (w & 3) * 16 + l16;
            f32x4 accp[2] = {{0.f,0.f,0.f,0.f},{0.f,0.f,0.f,0.f}};
            #pragma unroll
            for (int kcd = 0; kcd < 8; ++kcd) {
                bf16x8 bw = *reinterpret_cast<const bf16x8*>(
                    Wdblob + (size_t)((((w & 3) * 8 + kcd) * 64) + lane) * 8);
                #pragma unroll
                for (int m = 0; m < 2; ++m) {
                    bf16x8 a = *reinterpret_cast<const bf16x8*>(
                        A_s + (((2 + kcd) * 4 + (m4a + m)) * 64 + lane) * 8);
                    accp[m] = __builtin_amdgcn_mfma_f32_16x16x32_bf16(a, bw, accp[m], 0, 0, 0);
                }
            }
            const int kcx = f >> 5;
            const int lsh = (((f & 31) >> 3) & 3) << 4;
            #pragma unroll
            for (int m = 0; m < 2; ++m) {
                #pragma unroll
                for (int j = 0; j < 4; ++j) {
                    int row = (m4a + m) * 16 + hi4 * 4 + j;
                    float v = accp[m][j] + bdv;
                    if (ub == 0)
                        out[((size_t)(bb + row) * out_steps + s) * FDIM + f] = v;
                    A_s[((kcx * 4 + (row >> 4)) * 64 + ((row & 15) | lsh)) * 8 + (f & 7)] = f2bf(v);
                }
            }
            if (t == tmax) break;
            __syncthreads();                   // feedback x staged
        }

        // ================ z = [x|h] @ Wslice : weights resident ================
        f32x4 acc[2][4];
        #pragma unroll
        for (int m = 0; m < 2; ++m)
            #pragma unroll
            for (int g = 0; g < 4; ++g) acc[m][g] = (f32x4){0.f, 0.f, 0.f, 0.f};

        #pragma unroll
        for (int kc = 0; kc < NKC; ++kc) {
            bf16x8 a0 = *reinterpret_cast<const bf16x8*>(
                A_s + ((kc * 4 + m4a) * 64 + lane) * 8);
            bf16x8 a1 = *reinterpret_cast<const bf16x8*>(
                A_s + ((kc * 4 + m4a + 1) * 64 + lane) * 8);
            #pragma unroll
            for (int g = 0; g < 4; ++g) {
                bf16x8 bw = (kc < 6)
                    ? *reinterpret_cast<const bf16x8*>(
                          WL + (((kc * 4 + ug) * 4 + g) * 64 + lane) * 8)
                    : Breg[kc - 6][g];
                acc[0][g] = __builtin_amdgcn_mfma_f32_16x16x32_bf16(a0, bw, acc[0][g], 0, 0, 0);
                acc[1][g] = __builtin_amdgcn_mfma_f32_16x16x32_bf16(a1, bw, acc[1][g], 0, 0, 0);
            }
        }

        // ================ gates + state -> hst (LDS) ================
        const int kcb = (w & 3) >> 1;          // unit block-half
        const int lsh2 = ((((w & 3) & 1) * 2 + (l16 >> 3)) & 3) << 4;
        #pragma unroll
        for (int m = 0; m < 2; ++m) {
            #pragma unroll
            for (int j = 0; j < 4; ++j) {
                float zi = acc[m][0][j] + bz[0];
                float zf = acc[m][1][j] + bz[1];
                float zg = acc[m][2][j] + bz[2];
                float zo = acc[m][3][j] + bz[3];
                float ig = sigmoid_fast(zi);
                float fg = sigmoid_fast(zf);
                float og = sigmoid_fast(zo);
                float cn = fg * c_reg[m][j] + ig * tanh_fast(zg);
                c_reg[m][j] = cn;
                float hv = og * tanh_fast(cn);
                int rl = hi4 * 4 + j;
                hst[((kcb * 4 + (m4a + m)) * 64 + (rl | lsh2)) * 8 + (l16 & 7)] = f2bf(hv);
            }
        }
        __syncthreads();                       // hst complete; A reads done

        // ---- hst (8 KB) -> hbuf[1-p][rg] kc region (system-scope stores) ----
        {
            unsigned long long* dst = reinterpret_cast<unsigned long long*>(
                hbuf + (1 - p) * HB + (size_t)rg * 16384 + (size_t)(2 * ub) * 2048);
            const unsigned long long* src = reinterpret_cast<const unsigned long long*>(hst);
            sysstore(dst + tid,       src[tid]);
            sysstore(dst + 512 + tid, src[512 + tid]);
        }

        // ---- global barrier (relaxed system-scope counter) ----
        __syncthreads();                       // drains vmcnt: h stores complete
        if (tid == 0) {
            __hip_atomic_fetch_add(barcnt, 1u, __ATOMIC_RELAXED, __HIP_MEMORY_SCOPE_SYSTEM);
            const unsigned target = 256u * (unsigned)(t + 1);
            while (__hip_atomic_load(barcnt, __ATOMIC_RELAXED, __HIP_MEMORY_SCOPE_SYSTEM) < target)
                __builtin_amdgcn_s_sleep(2);
        }
        __syncthreads();                       // all threads released
    }
}

extern "C" void kernel_launch(void* const* d_in, const int* in_sizes, int n_in,
                              void* d_out, int out_size, void* d_ws, size_t ws_size,
                              hipStream_t stream) {
    const float* inputs = (const float*)d_in[0];
    const float* W      = (const float*)d_in[1];
    const float* U      = (const float*)d_in[2];
    const float* b      = (const float*)d_in[3];
    const float* Wd     = (const float*)d_in[4];
    const float* bd     = (const float*)d_in[5];
    float* out = (float*)d_out;

    const int out_steps = out_size / (BATCH * FDIM);   // 24

    char* ws = (char*)d_ws;
    unsigned short* Wblob  = (unsigned short*)(ws);               // 640 KB
    unsigned short* Wdblob = (unsigned short*)(ws + (1u << 20));  // 32 KB
    unsigned short* hbuf   = (unsigned short*)(ws + (2u << 20));  // 4 MB
    unsigned int*   barcnt = (unsigned int*)(ws + (6u << 20));    // 4 B

    prep_wblob<<<160, 256, 0, stream>>>(W, U, Wblob);
    prep_wdblob<<<8, 256, 0, stream>>>(Wd, Wdblob);
    hipMemsetAsync(hbuf, 0, (size_t)64 * 16384 * sizeof(unsigned short), stream); // parity 0
    hipMemsetAsync(barcnt, 0, sizeof(unsigned int), stream);

    (void)hipFuncSetAttribute((const void*)lstm_persistent,
                              hipFuncAttributeMaxDynamicSharedMemorySize, LDS_BYTES);

    lstm_persistent<<<dim3(256), dim3(512), LDS_BYTES, stream>>>(
        inputs, b, Wblob, Wdblob, bd, hbuf, barcnt, out, out_steps);
}

// Round 13
// 561.992 us; speedup vs baseline: 2.9676x; 1.8658x over previous
//
#include <hip/hip_runtime.h>
#include <math.h>

// ---------- problem constants ----------
constexpr int SEQ_T = 72;
constexpr int FDIM  = 64;
constexpr int UNITS = 256;
constexpr int U4    = 1024;
constexpr int BATCH = 4096;
constexpr int NKC   = 10;          // k-chunks of 32 (x: kc0-1, h: kc2-9)

// Partition: 256 blocks = 64 row-groups (64 rows) x 4 unit-groups (64 units x 4 gates).
// blk = rg + ub*64  ->  all 4 blocks of a group share blk%8 (same XCD, perf-only).
// Weights per block: 160 KB -> 96 KB LDS (kc0-5) + 64 VGPR/lane (kc6-9).
// h exchanged via L3 (AGENT-scope relaxed atomics); per-group (4-block) barrier.

// LDS (dynamic, shorts):
constexpr int A_SH    = NKC * 4 * 64 * 8;        // 20480 sh = 40960 B   [kc][m4][64][8]
constexpr int WL_SH   = 6 * 4 * 4 * 64 * 8;      // 49152 sh = 98304 B   [kc<6][ug][g][64][8]
constexpr int HST_SH  = 2 * 4 * 64 * 8;          // 4096 sh  = 8192 B    [kcb][m4][64][8]
constexpr int LDS_BYTES = (A_SH + WL_SH + HST_SH) * 2;   // 147456

using bf16x8 = __attribute__((ext_vector_type(8))) short;
using f32x4  = __attribute__((ext_vector_type(4))) float;

__device__ __forceinline__ float sigmoid_fast(float x) {
    return 1.0f / (1.0f + __expf(-x));
}
__device__ __forceinline__ float tanh_fast(float x) {
    float ax = fabsf(x);
    float e  = __expf(2.0f * ax);
    float t  = 1.0f - 2.0f / (e + 1.0f);
    return copysignf(t, x);
}
__device__ __forceinline__ unsigned short f2bf(float f) {
    union { float f; unsigned u; } v; v.f = f;
    unsigned r = (v.u + 0x7FFFu + ((v.u >> 16) & 1u)) >> 16;   // RNE
    return (unsigned short)r;
}
__device__ __forceinline__ bf16x8 pack8(float4 a, float4 b) {
    bf16x8 p;
    p[0] = (short)f2bf(a.x); p[1] = (short)f2bf(a.y);
    p[2] = (short)f2bf(a.z); p[3] = (short)f2bf(a.w);
    p[4] = (short)f2bf(b.x); p[5] = (short)f2bf(b.y);
    p[6] = (short)f2bf(b.z); p[7] = (short)f2bf(b.w);
    return p;
}

// ---------- prep: z-weights, blob idx = (((ub*10+kc)*4+ug)*4+g)*64 + l ----------
// col = g*256 + ub*64 + ug*16 + (l&15) ; k = kc*32 + (l>>4)*8 + e
__global__ void prep_wblob(const float* __restrict__ W, const float* __restrict__ U,
                           unsigned short* __restrict__ Wblob) {
    int id = blockIdx.x * 256 + threadIdx.x;    // 40960
    int l    = id & 63;
    int g    = (id >> 6) & 3;
    int ug   = (id >> 8) & 3;
    int rest = id >> 10;                         // ub*10 + kc
    int kc   = rest % 10, ub = rest / 10;
    int col  = g * 256 + ub * 64 + ug * 16 + (l & 15);
    int kb   = kc * 32 + (l >> 4) * 8;
    bf16x8 v;
    #pragma unroll
    for (int e = 0; e < 8; ++e) {
        int k = kb + e;
        float f = (k < FDIM) ? W[(size_t)k * U4 + col] : U[(size_t)(k - FDIM) * U4 + col];
        v[e] = (short)f2bf(f);
    }
    *reinterpret_cast<bf16x8*>(Wblob + (size_t)id * 8) = v;
}

// ---------- prep: dense weights, blob idx = (ft*8 + kcd)*64 + l ----------
__global__ void prep_wdblob(const float* __restrict__ Wd, unsigned short* __restrict__ Wdblob) {
    int id = blockIdx.x * 256 + threadIdx.x;    // 2048
    int l   = id & 63;
    int kcd = (id >> 6) & 7;
    int ft  = id >> 9;
    int f   = ft * 16 + (l & 15);
    int kb  = kcd * 32 + (l >> 4) * 8;
    bf16x8 v;
    #pragma unroll
    for (int e = 0; e < 8; ++e)
        v[e] = (short)f2bf(Wd[(size_t)(kb + e) * FDIM + f]);
    *reinterpret_cast<bf16x8*>(Wdblob + (size_t)id * 8) = v;
}

// AGENT-scope relaxed 8B load/store: bypass per-XCD L2, coherence point = L3.
__device__ __forceinline__ unsigned long long agload(const unsigned long long* p) {
    return __hip_atomic_load(p, __ATOMIC_RELAXED, __HIP_MEMORY_SCOPE_AGENT);
}
__device__ __forceinline__ void agstore(unsigned long long* p, unsigned long long v) {
    __hip_atomic_store(p, v, __ATOMIC_RELAXED, __HIP_MEMORY_SCOPE_AGENT);
}

// ---------- persistent unit-split LSTM: weights CU-resident ----------
// grid 256 x 512 (8 waves). rg = blk & 63, ub = blk >> 6. Block owns rows
// [rg*64,+64), units [ub*64,+64) x 4 gates. Wave w: ug = w&3, row-half = w>>2.
__global__ __launch_bounds__(512, 1) void lstm_persistent(
    const float* __restrict__ inputs,          // [B][72][64] fp32
    const float* __restrict__ bias,            // [1024] fp32
    const unsigned short* __restrict__ Wblob,  // z-weight blobs (640 KB)
    const unsigned short* __restrict__ Wdblob, // dense blobs (32 KB)
    const float* __restrict__ bd,              // [64] fp32
    unsigned short* __restrict__ hbuf,         // [2][64 rg][8 kc][4 m][64][8] bf16
    unsigned int* __restrict__ barcnt,         // [64 groups x 32] (128B-spaced)
    float* __restrict__ out,                   // [B][out_steps][64] fp32
    int out_steps)
{
    extern __shared__ char smem[];
    unsigned short* A_s = (unsigned short*)smem;                       // [10][4][64][8]
    unsigned short* WL  = (unsigned short*)(smem + A_SH * 2);          // [6][4][4][64][8]
    unsigned short* hst = (unsigned short*)(smem + (A_SH + WL_SH) * 2);// [2][4][64][8]

    const int tid  = threadIdx.x;
    const int w    = tid >> 6, lane = tid & 63;
    const int l16  = lane & 15, hi4 = lane >> 4;
    const int blk  = blockIdx.x;
    const int rg   = blk & 63, ub = blk >> 6;  // same-XCD groups (perf heuristic)
    const int bb   = rg * 64;
    const int ug   = w & 3;                    // wave's 16-unit group within block
    const int m4a  = 2 * (w >> 2);             // wave's two row-16 tiles

    // ---- LDS weights kc0-5: contiguous 96 KB from Wblob[ub] (once) ----
    {
        const unsigned short* src = Wblob + (size_t)(ub * 10) * 16 * 512;
        #pragma unroll
        for (int i = 0; i < 12; ++i) {
            int idx = (i * 512 + tid) * 8;     // 49152 shorts as 16B chunks
            *reinterpret_cast<bf16x8*>(WL + idx) =
                *reinterpret_cast<const bf16x8*>(src + idx);
        }
    }
    // ---- register weights kc6-9 (wave's ug slice): 64 VGPRs ----
    bf16x8 Breg[4][4];
    #pragma unroll
    for (int i = 0; i < 4; ++i)
        #pragma unroll
        for (int g = 0; g < 4; ++g)
            Breg[i][g] = *reinterpret_cast<const bf16x8*>(
                Wblob + ((size_t)(((ub * 10 + 6 + i) * 4 + ug) * 4 + g) * 64 + lane) * 8);

    const int uu = ub * 64 + ug * 16 + l16;    // this lane's global unit
    float bz[4];
    #pragma unroll
    for (int g = 0; g < 4; ++g) bz[g] = bias[g * 256 + uu];
    const float bdv = bd[(w & 3) * 16 + l16];  // dense: ft = w&3

    float c_reg[2][4];
    #pragma unroll
    for (int m = 0; m < 2; ++m)
        #pragma unroll
        for (int j = 0; j < 4; ++j) c_reg[m][j] = 0.0f;

    const int tmax = SEQ_T + out_steps - 1;    // 95
    const size_t HB = (size_t)64 * 16384;      // parity stride (shorts)

    #pragma unroll 1
    for (int t = 0; ; ++t) {
        const int p = t & 1;

        // ---- stage h_t -> A kc2-9 (t=0: zeros, no memset dependence) ----
        if (t == 0) {
            #pragma unroll
            for (int i = 0; i < 8; ++i)
                *reinterpret_cast<unsigned long long*>(A_s + 4096 + (i * 512 + tid) * 4) = 0ull;
        } else {
            const unsigned long long* src = reinterpret_cast<const unsigned long long*>(
                hbuf + p * HB + (size_t)rg * 16384);
            unsigned long long vbuf[8];
            #pragma unroll
            for (int i = 0; i < 8; ++i) vbuf[i] = agload(src + (size_t)i * 512 + tid);
            #pragma unroll
            for (int i = 0; i < 8; ++i)
                *reinterpret_cast<unsigned long long*>(A_s + 4096 + (i * 512 + tid) * 4) = vbuf[i];
        }
        if (t < SEQ_T) {
            // ---- stage x(t): 8 floats/thread -> A kc0,1 ----
            int r = tid >> 3, c8 = (tid & 7) * 8;
            const float* xr = inputs + ((size_t)(bb + r) * SEQ_T + t) * FDIM + c8;
            bf16x8 pk = pack8(*reinterpret_cast<const float4*>(xr),
                              *reinterpret_cast<const float4*>(xr + 4));
            int kcx = c8 >> 5;
            int lb  = (r & 15) | ((((c8 & 31) >> 3) & 3) << 4);
            *reinterpret_cast<bf16x8*>(A_s + ((kcx * 4 + (r >> 4)) * 64 + lb) * 8) = pk;
            __syncthreads();                   // A ready
        } else {
            __syncthreads();                   // h staged
            // ---- dense head (redundant in all 4 blocks): ft=w&3, rows m4a,m4a+1 ----
            const int s = t - SEQ_T;
            const int f = (w & 3) * 16 + l16;
            f32x4 accp[2] = {{0.f,0.f,0.f,0.f},{0.f,0.f,0.f,0.f}};
            #pragma unroll
            for (int kcd = 0; kcd < 8; ++kcd) {
                bf16x8 bw = *reinterpret_cast<const bf16x8*>(
                    Wdblob + (size_t)((((w & 3) * 8 + kcd) * 64) + lane) * 8);
                #pragma unroll
                for (int m = 0; m < 2; ++m) {
                    bf16x8 a = *reinterpret_cast<const bf16x8*>(
                        A_s + (((2 + kcd) * 4 + (m4a + m)) * 64 + lane) * 8);
                    accp[m] = __builtin_amdgcn_mfma_f32_16x16x32_bf16(a, bw, accp[m], 0, 0, 0);
                }
            }
            const int kcx = f >> 5;
            const int lsh = (((f & 31) >> 3) & 3) << 4;
            #pragma unroll
            for (int m = 0; m < 2; ++m) {
                #pragma unroll
                for (int j = 0; j < 4; ++j) {
                    int row = (m4a + m) * 16 + hi4 * 4 + j;
                    float v = accp[m][j] + bdv;
                    if (ub == 0)
                        out[((size_t)(bb + row) * out_steps + s) * FDIM + f] = v;
                    A_s[((kcx * 4 + (row >> 4)) * 64 + ((row & 15) | lsh)) * 8 + (f & 7)] = f2bf(v);
                }
            }
            if (t == tmax) break;
            __syncthreads();                   // feedback x staged
        }

        // ================ z = [x|h] @ Wslice : weights resident ================
        f32x4 acc[2][4];
        #pragma unroll
        for (int m = 0; m < 2; ++m)
            #pragma unroll
            for (int g = 0; g < 4; ++g) acc[m][g] = (f32x4){0.f, 0.f, 0.f, 0.f};

        #pragma unroll
        for (int kc = 0; kc < NKC; ++kc) {
            bf16x8 a0 = *reinterpret_cast<const bf16x8*>(
                A_s + ((kc * 4 + m4a) * 64 + lane) * 8);
            bf16x8 a1 = *reinterpret_cast<const bf16x8*>(
                A_s + ((kc * 4 + m4a + 1) * 64 + lane) * 8);
            #pragma unroll
            for (int g = 0; g < 4; ++g) {
                bf16x8 bw = (kc < 6)
                    ? *reinterpret_cast<const bf16x8*>(
                          WL + (((kc * 4 + ug) * 4 + g) * 64 + lane) * 8)
                    : Breg[kc - 6][g];
                acc[0][g] = __builtin_amdgcn_mfma_f32_16x16x32_bf16(a0, bw, acc[0][g], 0, 0, 0);
                acc[1][g] = __builtin_amdgcn_mfma_f32_16x16x32_bf16(a1, bw, acc[1][g], 0, 0, 0);
            }
        }

        // ================ gates + state -> hst (LDS) ================
        const int kcb = (w & 3) >> 1;          // unit block-half
        const int lsh2 = ((((w & 3) & 1) * 2 + (l16 >> 3)) & 3) << 4;
        #pragma unroll
        for (int m = 0; m < 2; ++m) {
            #pragma unroll
            for (int j = 0; j < 4; ++j) {
                float zi = acc[m][0][j] + bz[0];
                float zf = acc[m][1][j] + bz[1];
                float zg = acc[m][2][j] + bz[2];
                float zo = acc[m][3][j] + bz[3];
                float ig = sigmoid_fast(zi);
                float fg = sigmoid_fast(zf);
                float og = sigmoid_fast(zo);
                float cn = fg * c_reg[m][j] + ig * tanh_fast(zg);
                c_reg[m][j] = cn;
                float hv = og * tanh_fast(cn);
                int rl = hi4 * 4 + j;
                hst[((kcb * 4 + (m4a + m)) * 64 + (rl | lsh2)) * 8 + (l16 & 7)] = f2bf(hv);
            }
        }
        __syncthreads();                       // hst complete; A reads done

        // ---- hst (8 KB) -> hbuf[1-p][rg] (agent-scope stores, land in L3) ----
        {
            unsigned long long* dst = reinterpret_cast<unsigned long long*>(
                hbuf + (1 - p) * HB + (size_t)rg * 16384 + (size_t)(2 * ub) * 2048);
            const unsigned long long* src = reinterpret_cast<const unsigned long long*>(hst);
            agstore(dst + tid,       src[tid]);
            agstore(dst + 512 + tid, src[512 + tid]);
        }

        // ---- per-group barrier (4 blocks, relaxed agent-scope counter) ----
        __syncthreads();                       // drains vmcnt: h stores complete at L3
        if (tid == 0) {
            unsigned int* cnt = barcnt + rg * 32;      // 128B-spaced per group
            __hip_atomic_fetch_add(cnt, 1u, __ATOMIC_RELAXED, __HIP_MEMORY_SCOPE_AGENT);
            const unsigned target = 4u * (unsigned)(t + 1);
            while (__hip_atomic_load(cnt, __ATOMIC_RELAXED, __HIP_MEMORY_SCOPE_AGENT) < target)
                __builtin_amdgcn_s_sleep(2);
        }
        __syncthreads();                       // all threads released
    }
}

extern "C" void kernel_launch(void* const* d_in, const int* in_sizes, int n_in,
                              void* d_out, int out_size, void* d_ws, size_t ws_size,
                              hipStream_t stream) {
    const float* inputs = (const float*)d_in[0];
    const float* W      = (const float*)d_in[1];
    const float* U      = (const float*)d_in[2];
    const float* b      = (const float*)d_in[3];
    const float* Wd     = (const float*)d_in[4];
    const float* bd     = (const float*)d_in[5];
    float* out = (float*)d_out;

    const int out_steps = out_size / (BATCH * FDIM);   // 24

    char* ws = (char*)d_ws;
    unsigned short* Wblob  = (unsigned short*)(ws);               // 640 KB
    unsigned short* Wdblob = (unsigned short*)(ws + (1u << 20));  // 32 KB
    unsigned short* hbuf   = (unsigned short*)(ws + (2u << 20));  // 4 MB
    unsigned int*   barcnt = (unsigned int*)(ws + (6u << 20));    // 64 x 128 B

    prep_wblob<<<160, 256, 0, stream>>>(W, U, Wblob);
    prep_wdblob<<<8, 256, 0, stream>>>(Wd, Wdblob);
    hipMemsetAsync(barcnt, 0, 64 * 128, stream);

    (void)hipFuncSetAttribute((const void*)lstm_persistent,
                              hipFuncAttributeMaxDynamicSharedMemorySize, LDS_BYTES);

    lstm_persistent<<<dim3(256), dim3(512), LDS_BYTES, stream>>>(
        inputs, b, Wblob, Wdblob, bd, hbuf, barcnt, out, out_steps);
}